// Round 11
// baseline (158.493 us; speedup 1.0000x reference)
//
#include <hip/hip_runtime.h>
#include <stdint.h>

#define N_ROWS 4096
#define DIM    1024
#define NCLS   64
#define EPSV   0.1f

typedef __attribute__((ext_vector_type(4))) float f32x4;

__device__ __forceinline__ void async_cp16(const void* g, void* l) {
    __builtin_amdgcn_global_load_lds((const __attribute__((address_space(1))) void*)g,
                                     (__attribute__((address_space(3))) void*)l,
                                     16, 0, 0);
}

__device__ __forceinline__ float softplus(float x) {
    return fmaxf(x, 0.f) + __logf(1.f + __expf(-fabsf(x)));
}

// ---------------- K1: per-class stats + last-block weights tail --------------
// 256 blocks = (class c) x (dim quarter q). After writing its slice, each
// block bumps a device counter; the LAST block (release/acquire handshake)
// computes weights, the fp8 scale, and zeroes the loss — removing the
// separate k_weights launch + gap.
__global__ __launch_bounds__(256) void k_cstats_w(const float* __restrict__ X,
                                                  const int* __restrict__ tgt,
                                                  float* __restrict__ csumR,
                                                  float* __restrict__ csqR,
                                                  float* __restrict__ w,
                                                  float* __restrict__ scal,
                                                  float* __restrict__ loss_out,
                                                  unsigned int* __restrict__ done) {
    __shared__ int rows[N_ROWS];
    __shared__ int nrows_s;
    __shared__ int lastf;
    __shared__ int hist[NCLS];
    __shared__ float redw[4];
    int tid = threadIdx.x;
    int c = blockIdx.x >> 2, q = blockIdx.x & 3;
    if (tid == 0) nrows_s = 0;
    __syncthreads();
    for (int i = tid; i < N_ROWS; i += 256)
        if (tgt[i] == c) { int p = atomicAdd(&nrows_s, 1); rows[p] = i; }
    __syncthreads();
    int n = nrows_s;
    int d = q * 256 + tid;
    float s = 0.f, qq = 0.f;
    #pragma unroll 4
    for (int r = 0; r < n; r++) {
        float x = X[(size_t)rows[r] * DIM + d];
        s += x; qq += x * x;
    }
    csumR[c * DIM + d] = s;
    csqR [c * DIM + d] = qq;

    // completion handshake: exactly one block proceeds, no spinning
    __threadfence();
    if (tid == 0) lastf = (atomicAdd(done, 1u) == 255u);
    __syncthreads();
    if (!lastf) return;
    __threadfence();                       // acquire: see all slices

    if (tid < NCLS) hist[tid] = 0;
    __syncthreads();
    for (int i = tid; i < N_ROWS; i += 256) atomicAdd(&hist[tgt[i]], 1);
    __syncthreads();
    long long sp = 0, ss = 0;
    for (int cc = 0; cc < NCLS; cc++) { long long v = hist[cc]; sp += v * (v - 1); ss += v * v; }
    float cnt_pos = (float)sp;
    float cnt_neg = (float)((long long)N_ROWS * N_ROWS - ss);
    float m = 0.f;
    #pragma unroll
    for (int k = 0; k < 4; k++) {
        int dd = tid + k * 256;
        float A = 0.f, X2 = 0.f, T = 0.f, SS = 0.f;
        #pragma unroll 8
        for (int cc = 0; cc < NCLS; cc++) {
            float sv = csumR[cc * DIM + dd];
            float qv = csqR [cc * DIM + dd];
            A += (float)hist[cc] * qv; X2 += qv; T += sv; SS += sv * sv;
        }
        float posnum = 2.f * (A - SS);
        float negnum = 2.f * ((float)N_ROWS * X2 - A - T * T + SS);
        float wd = cnt_neg / (negnum + EPSV) - cnt_pos / (posnum + EPSV);
        w[dd] = wd;
        m += wd * wd;
    }
    for (int off = 32; off; off >>= 1) m += __shfl_down(m, off, 64);
    int wv = tid >> 6, ln = tid & 63;
    if (ln == 0) redw[wv] = m;
    __syncthreads();
    if (tid == 0) {
        float ms = (redw[0] + redw[1] + redw[2] + redw[3]) / 1024.f;
        scal[0] = exp2f(roundf(log2f(sqrtf(ms) + 1e-30f)));
        loss_out[0] = 0.0f;
    }
}

// ---------------- K2: xw, sq (fp32 exact), fp8 casts with baked swizzle ------
// Global fp8 layout: logical 8B quad qd stored at physical quad qd^((row>>2)&3)
// -> gemm's contiguous 16B staging yields conflict-free ds_read_b64 reads.
__global__ __launch_bounds__(256) void k_prep(const float* __restrict__ X,
                                              const float* __restrict__ w,
                                              const float* __restrict__ scal,
                                              unsigned int* __restrict__ Xb8,
                                              unsigned int* __restrict__ XWb8,
                                              float* __restrict__ sq) {
    int row = blockIdx.x, tid = threadIdx.x;
    float inv_sw = 1.0f / scal[0];
    float4 x  = ((const float4*)(X + (size_t)row * DIM))[tid];
    float4 ww = ((const float4*)w)[tid];
    float4 xw = make_float4(x.x * ww.x, x.y * ww.y, x.z * ww.z, x.w * ww.w);
    float p = x.x * xw.x + x.y * xw.y + x.z * xw.z + x.w * xw.w;
    unsigned ux = __builtin_amdgcn_cvt_pk_fp8_f32(x.x, x.y, 0, false);
    ux = __builtin_amdgcn_cvt_pk_fp8_f32(x.z, x.w, ux, true);
    unsigned uw = __builtin_amdgcn_cvt_pk_fp8_f32(xw.x * inv_sw, xw.y * inv_sw, 0, false);
    uw = __builtin_amdgcn_cvt_pk_fp8_f32(xw.z * inv_sw, xw.w * inv_sw, uw, true);
    int t = tid >> 3, qd = (tid >> 1) & 3, o = tid & 1;
    int s = (row >> 2) & 3;
    int widx = row * 256 + t * 8 + (qd ^ s) * 2 + o;
    Xb8 [widx] = ux;
    XWb8[widx] = uw;
    for (int off = 32; off; off >>= 1) p += __shfl_down(p, off, 64);
    __shared__ float red[4];
    int wv = tid >> 6, ln = tid & 63;
    if (ln == 0) red[wv] = p;
    __syncthreads();
    if (tid == 0) sq[row] = red[0] + red[1] + red[2] + red[3];
}

// ---------------- K3: fused fp8 MFMA gram + softplus + masked mean -----------
// 128x128 tiles, balanced groups (g owns jt in {g,15-g,16+g,31-g}; 528 blocks).
// 512 thr = 8 waves (2x4), wave = 64x32 (4x2 frags, acc = 32 AGPR).
// __launch_bounds__(512,6): 6 waves/SIMD -> <=85 unified regs -> 3 blocks/CU
// -> all 528 tiles co-resident (tail absorbed) + 50% more TLP than R10.
// Baked-global bank swizzle; depth-3 pipeline, raw s_barrier + manual vmcnt.
__global__ __launch_bounds__(512, 6) void k_gemm_loss(const unsigned char* __restrict__ Xb8,
                                                      const unsigned char* __restrict__ XWb8,
                                                      const float* __restrict__ sq,
                                                      const int* __restrict__ tgt,
                                                      const float* __restrict__ scal,
                                                      float* __restrict__ loss) {
    __shared__ __align__(16) unsigned char As[4][4096];
    __shared__ __align__(16) unsigned char Bs[4][4096];
    __shared__ float sqI[128], sqJ[128];
    __shared__ int   tIs[128], tJs[128];
    __shared__ float red[8];

    int tid = threadIdx.x;
    int wave = tid >> 6, lane = tid & 63;

    // balanced triangular decode
    int g = blockIdx.x & 7, s = blockIdx.x >> 3;
    int j0 = g, j1 = 15 - g, j2 = 16 + g;
    int n0 = j0 + 1, n1 = j1 + 1, n2 = j2 + 1;
    int jt, it;
    if      (s < n0)           { jt = j0; it = s; }
    else if (s < n0 + n1)      { jt = j1; it = s - n0; }
    else if (s < n0 + n1 + n2) { jt = j2; it = s - n0 - n1; }
    else                       { jt = 31 - g; it = s - n0 - n1 - n2; }

    // staging: waves 0-3 -> A slab, waves 4-7 -> B slab; 1 contiguous 16B
    // chunk per thread per step (global layout already bank-swizzled).
    bool isA = wave < 4;
    const unsigned char* srcb = (isA ? Xb8 : XWb8) + (size_t)((isA ? it : jt) * 128) * DIM;
    unsigned char* slab = isA ? &As[0][0] : &Bs[0][0];
    int ch = (wave & 3) * 64 + lane;
    int r = ch >> 1, h = ch & 1;
    const unsigned char* gp = srcb + (size_t)r * DIM + h * 16;
    unsigned char* lb = slab + (wave & 3) * 1024;        // wave-uniform base

    // fragment LDS offsets: physical quad = kq ^ ((row>>2)&3)
    int lr = lane & 15, kq = lane >> 4;
    int offA[4], offB[2];
    int wrow = (wave >> 2) * 64, wcol = (wave & 3) * 32;
    #pragma unroll
    for (int mi = 0; mi < 4; mi++) {
        int row = wrow + mi * 16 + lr;
        offA[mi] = row * 32 + (kq ^ ((row >> 2) & 3)) * 8;
    }
    #pragma unroll
    for (int nj = 0; nj < 2; nj++) {
        int col = wcol + nj * 16 + lr;
        offB[nj] = col * 32 + (kq ^ ((col >> 2) & 3)) * 8;
    }

    f32x4 acc[4][2];
    #pragma unroll
    for (int i = 0; i < 4; i++)
        #pragma unroll
        for (int j = 0; j < 2; j++) acc[i][j] = (f32x4){0.f, 0.f, 0.f, 0.f};

    // prologue: stage K-steps 0,1,2 into buffers 0,1,2 (3 loads in flight)
    #pragma unroll
    for (int st = 0; st < 3; st++) async_cp16(gp + st * 32, lb + st * 4096);

    for (int kk = 0; kk < 32; kk++) {
        if      (kk < 30)  asm volatile("s_waitcnt vmcnt(2)" ::: "memory");
        else if (kk == 30) asm volatile("s_waitcnt vmcnt(1)" ::: "memory");
        else               asm volatile("s_waitcnt vmcnt(0)" ::: "memory");
        asm volatile("s_barrier" ::: "memory");
        if (kk < 29)                        // prefetch kk+3 into buffer (kk+3)&3
            async_cp16(gp + (kk + 3) * 32, lb + ((kk + 3) & 3) * 4096);
        int rd = kk & 3;
        const unsigned char* Ab = As[rd];
        const unsigned char* Bb = Bs[rd];
        long long av[4], bv[2];
        #pragma unroll
        for (int i = 0; i < 4; i++) av[i] = *(const long long*)(Ab + offA[i]);
        #pragma unroll
        for (int j = 0; j < 2; j++) bv[j] = *(const long long*)(Bb + offB[j]);
        #pragma unroll
        for (int i = 0; i < 4; i++)
            #pragma unroll
            for (int j = 0; j < 2; j++)
                acc[i][j] = __builtin_amdgcn_mfma_f32_16x16x32_fp8_fp8(av[i], bv[j], acc[i][j], 0, 0, 0);
    }

    // epilogue: S = sq_i + sq_j - 2*sw*G', masked softplus, x2 off-diagonal
    __syncthreads();
    if (tid < 128)      { sqI[tid] = sq[it * 128 + tid]; tIs[tid] = tgt[it * 128 + tid]; }
    else if (tid < 256) { int u = tid - 128; sqJ[u] = sq[jt * 128 + u]; tJs[u] = tgt[jt * 128 + u]; }
    __syncthreads();

    float sw2 = 2.0f * scal[0];
    float sum = 0.f;
    bool diagTile = (it == jt);
    #pragma unroll
    for (int j = 0; j < 2; j++) {
        int col = wcol + j * 16 + (lane & 15);            // C/D: col = lane&15
        float sj = sqJ[col]; int tj = tJs[col];
        #pragma unroll
        for (int i = 0; i < 4; i++) {
            int rbase = wrow + i * 16 + (lane >> 4) * 4;  // C/D: row = quad*4+reg
            #pragma unroll
            for (int rr = 0; rr < 4; rr++) {
                int rowp = rbase + rr;
                float S = sqI[rowp] + sj - sw2 * acc[i][j][rr];
                float v;
                if (tIs[rowp] == tj) v = (diagTile && rowp == col) ? 0.f : softplus(-S);
                else                 v = softplus(S);
                sum += v;
            }
        }
    }
    float scale = (diagTile ? 1.f : 2.f) * (1.f / ((float)N_ROWS * (float)(N_ROWS - 1)));
    sum *= scale;
    for (int off = 32; off; off >>= 1) sum += __shfl_down(sum, off, 64);
    if (lane == 0) red[wave] = sum;
    __syncthreads();
    if (tid == 0) {
        float t = 0.f;
        #pragma unroll
        for (int wv = 0; wv < 8; wv++) t += red[wv];
        atomicAdd(loss, t);
    }
}

extern "C" void kernel_launch(void* const* d_in, const int* in_sizes, int n_in,
                              void* d_out, int out_size, void* d_ws, size_t ws_size,
                              hipStream_t stream) {
    const float* X  = (const float*)d_in[0];
    const int* tgt  = (const int*)d_in[1];
    float* out = (float*)d_out;
    char* ws = (char*)d_ws;
    const size_t MB = 1u << 20;

    float* w      = (float*)ws;                         // 4 KB
    float* sq     = (float*)(ws + 4096);                // 16 KB
    float* scal   = (float*)(ws + 24576);               // 4 B
    unsigned int* done = (unsigned int*)(ws + 28672);   // 4 B
    unsigned int* Xb8  = (unsigned int*)(ws + 1 * MB);  // 4 MB
    unsigned int* XWb8 = (unsigned int*)(ws + 5 * MB);  // 4 MB
    float* csumR  = (float*)(ws + 9 * MB);              // 256 KB
    float* csqR   = (float*)(ws + 9 * MB + 256 * 1024); // 256 KB

    hipMemsetAsync(done, 0, 4, stream);
    k_cstats_w<<<256,  256, 0, stream>>>(X, tgt, csumR, csqR, w, scal, out, done);
    k_prep    <<<4096, 256, 0, stream>>>(X, w, scal, Xb8, XWb8, sq);
    k_gemm_loss<<<528, 512, 0, stream>>>((const unsigned char*)Xb8, (const unsigned char*)XWb8,
                                         sq, tgt, scal, out);
}

// Round 12
// 131.113 us; speedup vs baseline: 1.2088x; 1.2088x over previous
//
#include <hip/hip_runtime.h>
#include <stdint.h>

#define N_ROWS 4096
#define DIM    1024
#define NCLS   64
#define EPSV   0.1f

typedef __attribute__((ext_vector_type(4))) float f32x4;

__device__ __forceinline__ void async_cp16(const void* g, void* l) {
    __builtin_amdgcn_global_load_lds((const __attribute__((address_space(1))) void*)g,
                                     (__attribute__((address_space(3))) void*)l,
                                     16, 0, 0);
}

__device__ __forceinline__ float softplus(float x) {
    return fmaxf(x, 0.f) + __logf(1.f + __expf(-fabsf(x)));
}

// ---------------- K1: streaming per-class partial sums (affine addresses) ----
// grid 256 = 8 dim-groups x 32 row-chunks; 128 thr; LDS 64KB accumulators.
// Row loop is affine (no dependent addressing) -> deep MLP, streams at BW.
// LDS adds are conflict-free: class t is wave-uniform per row, lanes hit
// consecutive banks.
__global__ __launch_bounds__(128) void k_stats(const float* __restrict__ X,
                                               const int* __restrict__ tgt,
                                               float* __restrict__ csum_p,
                                               float* __restrict__ csq_p) {
    __shared__ float csum[NCLS * 128];
    __shared__ float csq [NCLS * 128];
    __shared__ int   tch[128];
    int tid = threadIdx.x;
    int dg = blockIdx.x >> 5, ch = blockIdx.x & 31;
    int d = dg * 128 + tid;
    for (int c = 0; c < NCLS; c++) { csum[c * 128 + tid] = 0.f; csq[c * 128 + tid] = 0.f; }
    tch[tid] = tgt[ch * 128 + tid];
    __syncthreads();
    const float* xp = X + (size_t)(ch * 128) * DIM + d;
    #pragma unroll 8
    for (int r = 0; r < 128; r++) {
        float x = xp[(size_t)r * DIM];
        int t = tch[r];
        csum[t * 128 + tid] += x;
        csq [t * 128 + tid] += x * x;
    }
    __syncthreads();
    for (int c = 0; c < NCLS; c++) {
        csum_p[(size_t)(ch * NCLS + c) * DIM + d] = csum[c * 128 + tid];
        csq_p [(size_t)(ch * NCLS + c) * DIM + d] = csq [c * 128 + tid];
    }
}

// ---------------- K2: reduce partials over 32 chunks -------------------------
__global__ __launch_bounds__(256) void k_reduce(const float* __restrict__ csum_p,
                                                const float* __restrict__ csq_p,
                                                float* __restrict__ csumR,
                                                float* __restrict__ csqR) {
    int idx = blockIdx.x * 256 + threadIdx.x;   // (c,d) flat, 65536
    float s = 0.f, q = 0.f;
    #pragma unroll 8
    for (int ch = 0; ch < 32; ch++) {
        s += csum_p[(size_t)ch * NCLS * DIM + idx];
        q += csq_p [(size_t)ch * NCLS * DIM + idx];
    }
    csumR[idx] = s;
    csqR [idx] = q;
}

// ---------------- K3: counts + weights + fp8 scale + zero loss ---------------
__global__ __launch_bounds__(128) void k_weights(const int* __restrict__ tgt,
                                                 const float* __restrict__ csumR,
                                                 const float* __restrict__ csqR,
                                                 float* __restrict__ w,
                                                 float* __restrict__ scal,
                                                 float* __restrict__ loss_out) {
    __shared__ int hist[NCLS];
    __shared__ float redw[2];
    int tid = threadIdx.x, b = blockIdx.x;
    if (tid < NCLS) hist[tid] = 0;
    __syncthreads();
    for (int i = tid; i < N_ROWS; i += 128) atomicAdd(&hist[tgt[i]], 1);
    __syncthreads();
    long long sp = 0, ss = 0;
    for (int c = 0; c < NCLS; c++) { long long cc = hist[c]; sp += cc * (cc - 1); ss += cc * cc; }
    float cnt_pos = (float)sp;
    float cnt_neg = (float)((long long)N_ROWS * N_ROWS - ss);
    int d = b * 128 + tid;
    float A = 0.f, X2 = 0.f, T = 0.f, SS = 0.f;
    #pragma unroll 8
    for (int c = 0; c < NCLS; c++) {
        float s = csumR[c * DIM + d];
        float q = csqR [c * DIM + d];
        A += (float)hist[c] * q; X2 += q; T += s; SS += s * s;
    }
    float posnum = 2.f * (A - SS);
    float negnum = 2.f * ((float)N_ROWS * X2 - A - T * T + SS);
    float wd = cnt_neg / (negnum + EPSV) - cnt_pos / (posnum + EPSV);
    w[d] = wd;
    float m = wd * wd;
    for (int off = 32; off; off >>= 1) m += __shfl_down(m, off, 64);
    int wv = tid >> 6, ln = tid & 63;
    if (ln == 0) redw[wv] = m;
    __syncthreads();
    if (b == 0 && tid == 0) {
        float ms = (redw[0] + redw[1]) / 128.f;
        scal[0] = exp2f(roundf(log2f(sqrtf(ms) + 1e-30f)));
        loss_out[0] = 0.0f;
    }
}

// ---------------- K4: xw, sq (fp32 exact), fp8 casts with baked swizzle ------
// Global fp8 layout: logical 8B quad qd stored at physical quad qd^((row>>2)&3)
// -> gemm's contiguous 16B staging yields conflict-free ds_read_b64 reads.
__global__ __launch_bounds__(256) void k_prep(const float* __restrict__ X,
                                              const float* __restrict__ w,
                                              const float* __restrict__ scal,
                                              unsigned int* __restrict__ Xb8,
                                              unsigned int* __restrict__ XWb8,
                                              float* __restrict__ sq) {
    int row = blockIdx.x, tid = threadIdx.x;
    float inv_sw = 1.0f / scal[0];
    float4 x  = ((const float4*)(X + (size_t)row * DIM))[tid];
    float4 ww = ((const float4*)w)[tid];
    float4 xw = make_float4(x.x * ww.x, x.y * ww.y, x.z * ww.z, x.w * ww.w);
    float p = x.x * xw.x + x.y * xw.y + x.z * xw.z + x.w * xw.w;
    unsigned ux = __builtin_amdgcn_cvt_pk_fp8_f32(x.x, x.y, 0, false);
    ux = __builtin_amdgcn_cvt_pk_fp8_f32(x.z, x.w, ux, true);
    unsigned uw = __builtin_amdgcn_cvt_pk_fp8_f32(xw.x * inv_sw, xw.y * inv_sw, 0, false);
    uw = __builtin_amdgcn_cvt_pk_fp8_f32(xw.z * inv_sw, xw.w * inv_sw, uw, true);
    int t = tid >> 3, qd = (tid >> 1) & 3, o = tid & 1;
    int s = (row >> 2) & 3;
    int widx = row * 256 + t * 8 + (qd ^ s) * 2 + o;
    Xb8 [widx] = ux;
    XWb8[widx] = uw;
    for (int off = 32; off; off >>= 1) p += __shfl_down(p, off, 64);
    __shared__ float red[4];
    int wv = tid >> 6, ln = tid & 63;
    if (ln == 0) red[wv] = p;
    __syncthreads();
    if (tid == 0) sq[row] = red[0] + red[1] + red[2] + red[3];
}

// ---------------- K5: fused fp8 MFMA gram + softplus + masked mean -----------
// Exactly R10's measured-best config: 128x128 tiles, balanced groups, 512 thr
// = 8 waves (2x4), wave = 64x32 (4x2 frags), __launch_bounds__(512,4),
// baked-global bank swizzle, depth-3 pipeline, raw s_barrier + manual vmcnt.
__global__ __launch_bounds__(512, 4) void k_gemm_loss(const unsigned char* __restrict__ Xb8,
                                                      const unsigned char* __restrict__ XWb8,
                                                      const float* __restrict__ sq,
                                                      const int* __restrict__ tgt,
                                                      const float* __restrict__ scal,
                                                      float* __restrict__ loss) {
    __shared__ __align__(16) unsigned char As[4][4096];
    __shared__ __align__(16) unsigned char Bs[4][4096];
    __shared__ float sqI[128], sqJ[128];
    __shared__ int   tIs[128], tJs[128];
    __shared__ float red[8];

    int tid = threadIdx.x;
    int wave = tid >> 6, lane = tid & 63;

    // balanced triangular decode
    int g = blockIdx.x & 7, s = blockIdx.x >> 3;
    int j0 = g, j1 = 15 - g, j2 = 16 + g;
    int n0 = j0 + 1, n1 = j1 + 1, n2 = j2 + 1;
    int jt, it;
    if      (s < n0)           { jt = j0; it = s; }
    else if (s < n0 + n1)      { jt = j1; it = s - n0; }
    else if (s < n0 + n1 + n2) { jt = j2; it = s - n0 - n1; }
    else                       { jt = 31 - g; it = s - n0 - n1 - n2; }

    bool isA = wave < 4;
    const unsigned char* srcb = (isA ? Xb8 : XWb8) + (size_t)((isA ? it : jt) * 128) * DIM;
    unsigned char* slab = isA ? &As[0][0] : &Bs[0][0];
    int ch = (wave & 3) * 64 + lane;
    int r = ch >> 1, h = ch & 1;
    const unsigned char* gp = srcb + (size_t)r * DIM + h * 16;
    unsigned char* lb = slab + (wave & 3) * 1024;        // wave-uniform base

    int lr = lane & 15, kq = lane >> 4;
    int offA[4], offB[2];
    int wrow = (wave >> 2) * 64, wcol = (wave & 3) * 32;
    #pragma unroll
    for (int mi = 0; mi < 4; mi++) {
        int row = wrow + mi * 16 + lr;
        offA[mi] = row * 32 + (kq ^ ((row >> 2) & 3)) * 8;
    }
    #pragma unroll
    for (int nj = 0; nj < 2; nj++) {
        int col = wcol + nj * 16 + lr;
        offB[nj] = col * 32 + (kq ^ ((col >> 2) & 3)) * 8;
    }

    f32x4 acc[4][2];
    #pragma unroll
    for (int i = 0; i < 4; i++)
        #pragma unroll
        for (int j = 0; j < 2; j++) acc[i][j] = (f32x4){0.f, 0.f, 0.f, 0.f};

    #pragma unroll
    for (int st = 0; st < 3; st++) async_cp16(gp + st * 32, lb + st * 4096);

    for (int kk = 0; kk < 32; kk++) {
        if      (kk < 30)  asm volatile("s_waitcnt vmcnt(2)" ::: "memory");
        else if (kk == 30) asm volatile("s_waitcnt vmcnt(1)" ::: "memory");
        else               asm volatile("s_waitcnt vmcnt(0)" ::: "memory");
        asm volatile("s_barrier" ::: "memory");
        if (kk < 29)
            async_cp16(gp + (kk + 3) * 32, lb + ((kk + 3) & 3) * 4096);
        int rd = kk & 3;
        const unsigned char* Ab = As[rd];
        const unsigned char* Bb = Bs[rd];
        long long av[4], bv[2];
        #pragma unroll
        for (int i = 0; i < 4; i++) av[i] = *(const long long*)(Ab + offA[i]);
        #pragma unroll
        for (int j = 0; j < 2; j++) bv[j] = *(const long long*)(Bb + offB[j]);
        #pragma unroll
        for (int i = 0; i < 4; i++)
            #pragma unroll
            for (int j = 0; j < 2; j++)
                acc[i][j] = __builtin_amdgcn_mfma_f32_16x16x32_fp8_fp8(av[i], bv[j], acc[i][j], 0, 0, 0);
    }

    __syncthreads();
    if (tid < 128)      { sqI[tid] = sq[it * 128 + tid]; tIs[tid] = tgt[it * 128 + tid]; }
    else if (tid < 256) { int u = tid - 128; sqJ[u] = sq[jt * 128 + u]; tJs[u] = tgt[jt * 128 + u]; }
    __syncthreads();

    float sw2 = 2.0f * scal[0];
    float sum = 0.f;
    bool diagTile = (it == jt);
    #pragma unroll
    for (int j = 0; j < 2; j++) {
        int col = wcol + j * 16 + (lane & 15);            // C/D: col = lane&15
        float sj = sqJ[col]; int tj = tJs[col];
        #pragma unroll
        for (int i = 0; i < 4; i++) {
            int rbase = wrow + i * 16 + (lane >> 4) * 4;  // C/D: row = quad*4+reg
            #pragma unroll
            for (int rr = 0; rr < 4; rr++) {
                int rowp = rbase + rr;
                float S = sqI[rowp] + sj - sw2 * acc[i][j][rr];
                float v;
                if (tIs[rowp] == tj) v = (diagTile && rowp == col) ? 0.f : softplus(-S);
                else                 v = softplus(S);
                sum += v;
            }
        }
    }
    float scale = (diagTile ? 1.f : 2.f) * (1.f / ((float)N_ROWS * (float)(N_ROWS - 1)));
    sum *= scale;
    for (int off = 32; off; off >>= 1) sum += __shfl_down(sum, off, 64);
    if (lane == 0) red[wave] = sum;
    __syncthreads();
    if (tid == 0) {
        float t = 0.f;
        #pragma unroll
        for (int wv = 0; wv < 8; wv++) t += red[wv];
        atomicAdd(loss, t);
    }
}

extern "C" void kernel_launch(void* const* d_in, const int* in_sizes, int n_in,
                              void* d_out, int out_size, void* d_ws, size_t ws_size,
                              hipStream_t stream) {
    const float* X  = (const float*)d_in[0];
    const int* tgt  = (const int*)d_in[1];
    float* out = (float*)d_out;
    char* ws = (char*)d_ws;
    const size_t MB = 1u << 20;

    float* w      = (float*)ws;                          // 4 KB
    float* sq     = (float*)(ws + 4096);                 // 16 KB
    float* scal   = (float*)(ws + 24576);                // 4 B
    unsigned int* Xb8  = (unsigned int*)(ws + 1 * MB);   // 4 MB
    unsigned int* XWb8 = (unsigned int*)(ws + 5 * MB);   // 4 MB
    float* csum_p = (float*)(ws + 9 * MB);               // 8 MB
    float* csq_p  = (float*)(ws + 17 * MB);              // 8 MB
    float* csumR  = (float*)(ws + 25 * MB);              // 256 KB
    float* csqR   = (float*)(ws + 25 * MB + 256 * 1024); // 256 KB

    k_stats   <<<256,  128, 0, stream>>>(X, tgt, csum_p, csq_p);
    k_reduce  <<<256,  256, 0, stream>>>(csum_p, csq_p, csumR, csqR);
    k_weights <<<8,    128, 0, stream>>>(tgt, csumR, csqR, w, scal, out);
    k_prep    <<<4096, 256, 0, stream>>>(X, w, scal, Xb8, XWb8, sq);
    k_gemm_loss<<<528, 512, 0, stream>>>((const unsigned char*)Xb8, (const unsigned char*)XWb8,
                                         sq, tgt, scal, out);
}

// Round 13
// 123.883 us; speedup vs baseline: 1.2794x; 1.0584x over previous
//
#include <hip/hip_runtime.h>
#include <stdint.h>

#define N_ROWS 4096
#define DIM    1024
#define NCLS   64
#define EPSV   0.1f

typedef __attribute__((ext_vector_type(4))) float f32x4;

__device__ __forceinline__ void async_cp16(const void* g, void* l) {
    __builtin_amdgcn_global_load_lds((const __attribute__((address_space(1))) void*)g,
                                     (__attribute__((address_space(3))) void*)l,
                                     16, 0, 0);
}

__device__ __forceinline__ float softplus(float x) {
    return fmaxf(x, 0.f) + __logf(1.f + __expf(-fabsf(x)));
}

// ---------------- K1: per-class sum/sqsum via row gather (R10 config) --------
__global__ __launch_bounds__(256) void k_cstats(const float* __restrict__ X,
                                                const int* __restrict__ tgt,
                                                float* __restrict__ csumR,
                                                float* __restrict__ csqR) {
    __shared__ int rows[N_ROWS];
    __shared__ int nrows_s;
    int tid = threadIdx.x;
    int c = blockIdx.x >> 2, q = blockIdx.x & 3;
    if (tid == 0) nrows_s = 0;
    __syncthreads();
    for (int i = tid; i < N_ROWS; i += 256)
        if (tgt[i] == c) { int p = atomicAdd(&nrows_s, 1); rows[p] = i; }
    __syncthreads();
    int n = nrows_s;
    int d = q * 256 + tid;
    float s = 0.f, qq = 0.f;
    #pragma unroll 4
    for (int r = 0; r < n; r++) {
        float x = X[(size_t)rows[r] * DIM + d];
        s += x; qq += x * x;
    }
    csumR[c * DIM + d] = s;
    csqR [c * DIM + d] = qq;
}

// ---------------- K2: counts + weights + fp8 scale + zero loss ---------------
__global__ __launch_bounds__(128) void k_weights(const int* __restrict__ tgt,
                                                 const float* __restrict__ csumR,
                                                 const float* __restrict__ csqR,
                                                 float* __restrict__ w,
                                                 float* __restrict__ scal,
                                                 float* __restrict__ loss_out) {
    __shared__ int hist[NCLS];
    __shared__ float redw[2];
    int tid = threadIdx.x, b = blockIdx.x;
    if (tid < NCLS) hist[tid] = 0;
    __syncthreads();
    for (int i = tid; i < N_ROWS; i += 128) atomicAdd(&hist[tgt[i]], 1);
    __syncthreads();
    long long sp = 0, ss = 0;
    for (int c = 0; c < NCLS; c++) { long long cc = hist[c]; sp += cc * (cc - 1); ss += cc * cc; }
    float cnt_pos = (float)sp;
    float cnt_neg = (float)((long long)N_ROWS * N_ROWS - ss);
    int d = b * 128 + tid;
    float A = 0.f, X2 = 0.f, T = 0.f, SS = 0.f;
    #pragma unroll 8
    for (int c = 0; c < NCLS; c++) {
        float s = csumR[c * DIM + d];
        float q = csqR [c * DIM + d];
        A += (float)hist[c] * q; X2 += q; T += s; SS += s * s;
    }
    float posnum = 2.f * (A - SS);
    float negnum = 2.f * ((float)N_ROWS * X2 - A - T * T + SS);
    float wd = cnt_neg / (negnum + EPSV) - cnt_pos / (posnum + EPSV);
    w[d] = wd;
    float m = wd * wd;
    for (int off = 32; off; off >>= 1) m += __shfl_down(m, off, 64);
    int wv = tid >> 6, ln = tid & 63;
    if (ln == 0) redw[wv] = m;
    __syncthreads();
    if (b == 0 && tid == 0) {
        float ms = (redw[0] + redw[1]) / 128.f;
        scal[0] = exp2f(roundf(log2f(sqrtf(ms) + 1e-30f)));
        loss_out[0] = 0.0f;
    }
}

// ---------------- K3: xw, sq (fp32 exact), fp8 casts with baked swizzle ------
__global__ __launch_bounds__(256) void k_prep(const float* __restrict__ X,
                                              const float* __restrict__ w,
                                              const float* __restrict__ scal,
                                              unsigned int* __restrict__ Xb8,
                                              unsigned int* __restrict__ XWb8,
                                              float* __restrict__ sq) {
    int row = blockIdx.x, tid = threadIdx.x;
    float inv_sw = 1.0f / scal[0];
    float4 x  = ((const float4*)(X + (size_t)row * DIM))[tid];
    float4 ww = ((const float4*)w)[tid];
    float4 xw = make_float4(x.x * ww.x, x.y * ww.y, x.z * ww.z, x.w * ww.w);
    float p = x.x * xw.x + x.y * xw.y + x.z * xw.z + x.w * xw.w;
    unsigned ux = __builtin_amdgcn_cvt_pk_fp8_f32(x.x, x.y, 0, false);
    ux = __builtin_amdgcn_cvt_pk_fp8_f32(x.z, x.w, ux, true);
    unsigned uw = __builtin_amdgcn_cvt_pk_fp8_f32(xw.x * inv_sw, xw.y * inv_sw, 0, false);
    uw = __builtin_amdgcn_cvt_pk_fp8_f32(xw.z * inv_sw, xw.w * inv_sw, uw, true);
    int t = tid >> 3, qd = (tid >> 1) & 3, o = tid & 1;
    int s = (row >> 2) & 3;
    int widx = row * 256 + t * 8 + (qd ^ s) * 2 + o;
    Xb8 [widx] = ux;
    XWb8[widx] = uw;
    for (int off = 32; off; off >>= 1) p += __shfl_down(p, off, 64);
    __shared__ float red[4];
    int wv = tid >> 6, ln = tid & 63;
    if (ln == 0) red[wv] = p;
    __syncthreads();
    if (tid == 0) sq[row] = red[0] + red[1] + red[2] + red[3];
}

// ---------------- K4: fused fp8 MFMA gram + softplus + masked mean -----------
// R10 structure with __launch_bounds__(512,6): 6 waves/SIMD -> <=85 unified
// regs -> 3 blocks/CU (24 waves/CU) -> 528 tiles in ~2 rounds, +50% TLP.
// 128x128 tiles, balanced groups, 8 waves (2x4), wave = 64x32 (4x2 frags),
// baked-global bank swizzle, depth-3 pipeline, raw s_barrier + manual vmcnt.
__global__ __launch_bounds__(512, 6) void k_gemm_loss(const unsigned char* __restrict__ Xb8,
                                                      const unsigned char* __restrict__ XWb8,
                                                      const float* __restrict__ sq,
                                                      const int* __restrict__ tgt,
                                                      const float* __restrict__ scal,
                                                      float* __restrict__ loss) {
    __shared__ __align__(16) unsigned char As[4][4096];
    __shared__ __align__(16) unsigned char Bs[4][4096];
    __shared__ float sqI[128], sqJ[128];
    __shared__ int   tIs[128], tJs[128];
    __shared__ float red[8];

    int tid = threadIdx.x;
    int wave = tid >> 6, lane = tid & 63;

    // balanced triangular decode
    int g = blockIdx.x & 7, s = blockIdx.x >> 3;
    int j0 = g, j1 = 15 - g, j2 = 16 + g;
    int n0 = j0 + 1, n1 = j1 + 1, n2 = j2 + 1;
    int jt, it;
    if      (s < n0)           { jt = j0; it = s; }
    else if (s < n0 + n1)      { jt = j1; it = s - n0; }
    else if (s < n0 + n1 + n2) { jt = j2; it = s - n0 - n1; }
    else                       { jt = 31 - g; it = s - n0 - n1 - n2; }

    bool isA = wave < 4;
    const unsigned char* srcb = (isA ? Xb8 : XWb8) + (size_t)((isA ? it : jt) * 128) * DIM;
    unsigned char* slab = isA ? &As[0][0] : &Bs[0][0];
    int ch = (wave & 3) * 64 + lane;
    int r = ch >> 1, h = ch & 1;
    const unsigned char* gp = srcb + (size_t)r * DIM + h * 16;
    unsigned char* lb = slab + (wave & 3) * 1024;        // wave-uniform base

    int lr = lane & 15, kq = lane >> 4;
    int offA[4], offB[2];
    int wrow = (wave >> 2) * 64, wcol = (wave & 3) * 32;
    #pragma unroll
    for (int mi = 0; mi < 4; mi++) {
        int row = wrow + mi * 16 + lr;
        offA[mi] = row * 32 + (kq ^ ((row >> 2) & 3)) * 8;
    }
    #pragma unroll
    for (int nj = 0; nj < 2; nj++) {
        int col = wcol + nj * 16 + lr;
        offB[nj] = col * 32 + (kq ^ ((col >> 2) & 3)) * 8;
    }

    f32x4 acc[4][2];
    #pragma unroll
    for (int i = 0; i < 4; i++)
        #pragma unroll
        for (int j = 0; j < 2; j++) acc[i][j] = (f32x4){0.f, 0.f, 0.f, 0.f};

    #pragma unroll
    for (int st = 0; st < 3; st++) async_cp16(gp + st * 32, lb + st * 4096);

    for (int kk = 0; kk < 32; kk++) {
        if      (kk < 30)  asm volatile("s_waitcnt vmcnt(2)" ::: "memory");
        else if (kk == 30) asm volatile("s_waitcnt vmcnt(1)" ::: "memory");
        else               asm volatile("s_waitcnt vmcnt(0)" ::: "memory");
        asm volatile("s_barrier" ::: "memory");
        if (kk < 29)
            async_cp16(gp + (kk + 3) * 32, lb + ((kk + 3) & 3) * 4096);
        int rd = kk & 3;
        const unsigned char* Ab = As[rd];
        const unsigned char* Bb = Bs[rd];
        long long av[4], bv[2];
        #pragma unroll
        for (int i = 0; i < 4; i++) av[i] = *(const long long*)(Ab + offA[i]);
        #pragma unroll
        for (int j = 0; j < 2; j++) bv[j] = *(const long long*)(Bb + offB[j]);
        #pragma unroll
        for (int i = 0; i < 4; i++)
            #pragma unroll
            for (int j = 0; j < 2; j++)
                acc[i][j] = __builtin_amdgcn_mfma_f32_16x16x32_fp8_fp8(av[i], bv[j], acc[i][j], 0, 0, 0);
    }

    __syncthreads();
    if (tid < 128)      { sqI[tid] = sq[it * 128 + tid]; tIs[tid] = tgt[it * 128 + tid]; }
    else if (tid < 256) { int u = tid - 128; sqJ[u] = sq[jt * 128 + u]; tJs[u] = tgt[jt * 128 + u]; }
    __syncthreads();

    float sw2 = 2.0f * scal[0];
    float sum = 0.f;
    bool diagTile = (it == jt);
    #pragma unroll
    for (int j = 0; j < 2; j++) {
        int col = wcol + j * 16 + (lane & 15);            // C/D: col = lane&15
        float sj = sqJ[col]; int tj = tJs[col];
        #pragma unroll
        for (int i = 0; i < 4; i++) {
            int rbase = wrow + i * 16 + (lane >> 4) * 4;  // C/D: row = quad*4+reg
            #pragma unroll
            for (int rr = 0; rr < 4; rr++) {
                int rowp = rbase + rr;
                float S = sqI[rowp] + sj - sw2 * acc[i][j][rr];
                float v;
                if (tIs[rowp] == tj) v = (diagTile && rowp == col) ? 0.f : softplus(-S);
                else                 v = softplus(S);
                sum += v;
            }
        }
    }
    float scale = (diagTile ? 1.f : 2.f) * (1.f / ((float)N_ROWS * (float)(N_ROWS - 1)));
    sum *= scale;
    for (int off = 32; off; off >>= 1) sum += __shfl_down(sum, off, 64);
    if (lane == 0) red[wave] = sum;
    __syncthreads();
    if (tid == 0) {
        float t = 0.f;
        #pragma unroll
        for (int wv = 0; wv < 8; wv++) t += red[wv];
        atomicAdd(loss, t);
    }
}

extern "C" void kernel_launch(void* const* d_in, const int* in_sizes, int n_in,
                              void* d_out, int out_size, void* d_ws, size_t ws_size,
                              hipStream_t stream) {
    const float* X  = (const float*)d_in[0];
    const int* tgt  = (const int*)d_in[1];
    float* out = (float*)d_out;
    char* ws = (char*)d_ws;
    const size_t MB = 1u << 20;

    float* w      = (float*)ws;                         // 4 KB
    float* sq     = (float*)(ws + 4096);                // 16 KB
    float* scal   = (float*)(ws + 24576);               // 4 B
    unsigned int* Xb8  = (unsigned int*)(ws + 1 * MB);  // 4 MB
    unsigned int* XWb8 = (unsigned int*)(ws + 5 * MB);  // 4 MB
    float* csumR  = (float*)(ws + 9 * MB);              // 256 KB
    float* csqR   = (float*)(ws + 9 * MB + 256 * 1024); // 256 KB

    k_cstats  <<<256,  256, 0, stream>>>(X, tgt, csumR, csqR);
    k_weights <<<8,    128, 0, stream>>>(tgt, csumR, csqR, w, scal, out);
    k_prep    <<<4096, 256, 0, stream>>>(X, w, scal, Xb8, XWb8, sq);
    k_gemm_loss<<<528, 512, 0, stream>>>((const unsigned char*)Xb8, (const unsigned char*)XWb8,
                                         sq, tgt, scal, out);
}

// Round 14
// 116.144 us; speedup vs baseline: 1.3646x; 1.0666x over previous
//
#include <hip/hip_runtime.h>
#include <stdint.h>

#define N_ROWS 4096
#define DIM    1024
#define NCLS   64
#define EPSV   0.1f

typedef __attribute__((ext_vector_type(4))) float f32x4;

__device__ __forceinline__ void async_cp16(const void* g, void* l) {
    __builtin_amdgcn_global_load_lds((const __attribute__((address_space(1))) void*)g,
                                     (__attribute__((address_space(3))) void*)l,
                                     16, 0, 0);
}

__device__ __forceinline__ float softplus(float x) {
    return fmaxf(x, 0.f) + __logf(1.f + __expf(-fabsf(x)));
}

// ---------------- K1: per-class sum/sqsum via row gather (R10 config) --------
__global__ __launch_bounds__(256) void k_cstats(const float* __restrict__ X,
                                                const int* __restrict__ tgt,
                                                float* __restrict__ csumR,
                                                float* __restrict__ csqR) {
    __shared__ int rows[N_ROWS];
    __shared__ int nrows_s;
    int tid = threadIdx.x;
    int c = blockIdx.x >> 2, q = blockIdx.x & 3;
    if (tid == 0) nrows_s = 0;
    __syncthreads();
    for (int i = tid; i < N_ROWS; i += 256)
        if (tgt[i] == c) { int p = atomicAdd(&nrows_s, 1); rows[p] = i; }
    __syncthreads();
    int n = nrows_s;
    int d = q * 256 + tid;
    float s = 0.f, qq = 0.f;
    #pragma unroll 4
    for (int r = 0; r < n; r++) {
        float x = X[(size_t)rows[r] * DIM + d];
        s += x; qq += x * x;
    }
    csumR[c * DIM + d] = s;
    csqR [c * DIM + d] = qq;
}

// ---------------- K2: counts + weights + fp8 scale + zero loss ---------------
__global__ __launch_bounds__(128) void k_weights(const int* __restrict__ tgt,
                                                 const float* __restrict__ csumR,
                                                 const float* __restrict__ csqR,
                                                 float* __restrict__ w,
                                                 float* __restrict__ scal,
                                                 float* __restrict__ loss_out) {
    __shared__ int hist[NCLS];
    __shared__ float redw[2];
    int tid = threadIdx.x, b = blockIdx.x;
    if (tid < NCLS) hist[tid] = 0;
    __syncthreads();
    for (int i = tid; i < N_ROWS; i += 128) atomicAdd(&hist[tgt[i]], 1);
    __syncthreads();
    long long sp = 0, ss = 0;
    for (int c = 0; c < NCLS; c++) { long long cc = hist[c]; sp += cc * (cc - 1); ss += cc * cc; }
    float cnt_pos = (float)sp;
    float cnt_neg = (float)((long long)N_ROWS * N_ROWS - ss);
    int d = b * 128 + tid;
    float A = 0.f, X2 = 0.f, T = 0.f, SS = 0.f;
    #pragma unroll 8
    for (int c = 0; c < NCLS; c++) {
        float s = csumR[c * DIM + d];
        float q = csqR [c * DIM + d];
        A += (float)hist[c] * q; X2 += q; T += s; SS += s * s;
    }
    float posnum = 2.f * (A - SS);
    float negnum = 2.f * ((float)N_ROWS * X2 - A - T * T + SS);
    float wd = cnt_neg / (negnum + EPSV) - cnt_pos / (posnum + EPSV);
    w[d] = wd;
    float m = wd * wd;
    for (int off = 32; off; off >>= 1) m += __shfl_down(m, off, 64);
    int wv = tid >> 6, ln = tid & 63;
    if (ln == 0) redw[wv] = m;
    __syncthreads();
    if (b == 0 && tid == 0) {
        float ms = (redw[0] + redw[1]) / 128.f;
        scal[0] = exp2f(roundf(log2f(sqrtf(ms) + 1e-30f)));
        loss_out[0] = 0.0f;
    }
}

// ---------------- K3: xw, sq (fp32 exact), fp8 casts with baked swizzle ------
__global__ __launch_bounds__(256) void k_prep(const float* __restrict__ X,
                                              const float* __restrict__ w,
                                              const float* __restrict__ scal,
                                              unsigned int* __restrict__ Xb8,
                                              unsigned int* __restrict__ XWb8,
                                              float* __restrict__ sq) {
    int row = blockIdx.x, tid = threadIdx.x;
    float inv_sw = 1.0f / scal[0];
    float4 x  = ((const float4*)(X + (size_t)row * DIM))[tid];
    float4 ww = ((const float4*)w)[tid];
    float4 xw = make_float4(x.x * ww.x, x.y * ww.y, x.z * ww.z, x.w * ww.w);
    float p = x.x * xw.x + x.y * xw.y + x.z * xw.z + x.w * xw.w;
    unsigned ux = __builtin_amdgcn_cvt_pk_fp8_f32(x.x, x.y, 0, false);
    ux = __builtin_amdgcn_cvt_pk_fp8_f32(x.z, x.w, ux, true);
    unsigned uw = __builtin_amdgcn_cvt_pk_fp8_f32(xw.x * inv_sw, xw.y * inv_sw, 0, false);
    uw = __builtin_amdgcn_cvt_pk_fp8_f32(xw.z * inv_sw, xw.w * inv_sw, uw, true);
    int t = tid >> 3, qd = (tid >> 1) & 3, o = tid & 1;
    int s = (row >> 2) & 3;
    int widx = row * 256 + t * 8 + (qd ^ s) * 2 + o;
    Xb8 [widx] = ux;
    XWb8[widx] = uw;
    for (int off = 32; off; off >>= 1) p += __shfl_down(p, off, 64);
    __shared__ float red[4];
    int wv = tid >> 6, ln = tid & 63;
    if (ln == 0) red[wv] = p;
    __syncthreads();
    if (tid == 0) sq[row] = red[0] + red[1] + red[2] + red[3];
}

// ---------------- K4: fused fp8 MFMA gram + softplus + masked mean -----------
// R10 layout/config with HALF the barriers: 16 phases x 2 K-steps. 6 step-
// buffers (step s -> buffer s%6; pair p%3 cyclic => prefetch target pair was
// retired at phase p-1, WAR-safe). Per wave-phase: 16 MFMA + 12 ds_read_b64;
// 2 staging loads/thread/phase, steady-state s_waitcnt vmcnt(2).
// 512 thr = 8 waves (2x4), wave = 64x32 (4x2 frags), __launch_bounds__(512,4),
// baked-global bank swizzle (conflict-free 32B-stride layout).
__global__ __launch_bounds__(512, 4) void k_gemm_loss(const unsigned char* __restrict__ Xb8,
                                                      const unsigned char* __restrict__ XWb8,
                                                      const float* __restrict__ sq,
                                                      const int* __restrict__ tgt,
                                                      const float* __restrict__ scal,
                                                      float* __restrict__ loss) {
    __shared__ __align__(16) unsigned char As[6][4096];
    __shared__ __align__(16) unsigned char Bs[6][4096];
    __shared__ float sqI[128], sqJ[128];
    __shared__ int   tIs[128], tJs[128];
    __shared__ float red[8];

    int tid = threadIdx.x;
    int wave = tid >> 6, lane = tid & 63;

    // balanced triangular decode
    int g = blockIdx.x & 7, s = blockIdx.x >> 3;
    int j0 = g, j1 = 15 - g, j2 = 16 + g;
    int n0 = j0 + 1, n1 = j1 + 1, n2 = j2 + 1;
    int jt, it;
    if      (s < n0)           { jt = j0; it = s; }
    else if (s < n0 + n1)      { jt = j1; it = s - n0; }
    else if (s < n0 + n1 + n2) { jt = j2; it = s - n0 - n1; }
    else                       { jt = 31 - g; it = s - n0 - n1 - n2; }

    // staging: waves 0-3 -> A slab, waves 4-7 -> B slab; 1 contiguous 16B
    // chunk per thread per K-step (global layout already bank-swizzled).
    bool isA = wave < 4;
    const unsigned char* srcb = (isA ? Xb8 : XWb8) + (size_t)((isA ? it : jt) * 128) * DIM;
    unsigned char* slab = isA ? &As[0][0] : &Bs[0][0];
    int ch = (wave & 3) * 64 + lane;
    int r = ch >> 1, h = ch & 1;
    const unsigned char* gp = srcb + (size_t)r * DIM + h * 16;
    unsigned char* lb = slab + (wave & 3) * 1024;        // wave-uniform base

    // fragment LDS offsets: physical quad = kq ^ ((row>>2)&3)
    int lr = lane & 15, kq = lane >> 4;
    int offA[4], offB[2];
    int wrow = (wave >> 2) * 64, wcol = (wave & 3) * 32;
    #pragma unroll
    for (int mi = 0; mi < 4; mi++) {
        int row = wrow + mi * 16 + lr;
        offA[mi] = row * 32 + (kq ^ ((row >> 2) & 3)) * 8;
    }
    #pragma unroll
    for (int nj = 0; nj < 2; nj++) {
        int col = wcol + nj * 16 + lr;
        offB[nj] = col * 32 + (kq ^ ((col >> 2) & 3)) * 8;
    }

    f32x4 acc[4][2];
    #pragma unroll
    for (int i = 0; i < 4; i++)
        #pragma unroll
        for (int j = 0; j < 2; j++) acc[i][j] = (f32x4){0.f, 0.f, 0.f, 0.f};

    // prologue: stage phases 0,1 = K-steps 0..3 into buffers 0..3
    #pragma unroll
    for (int st = 0; st < 4; st++) async_cp16(gp + st * 32, lb + st * 4096);

    for (int p = 0; p < 16; p++) {
        // need this phase's 2 loads done; leave next phase's 2 in flight
        if (p < 15) asm volatile("s_waitcnt vmcnt(2)" ::: "memory");
        else        asm volatile("s_waitcnt vmcnt(0)" ::: "memory");
        asm volatile("s_barrier" ::: "memory");
        if (p < 14) {                       // prefetch phase p+2 (steps 2p+4,2p+5)
            int s0 = 2 * p + 4;
            async_cp16(gp + (size_t)s0 * 32, lb + (s0 % 6) * 4096);
            async_cp16(gp + (size_t)(s0 + 1) * 32, lb + ((s0 + 1) % 6) * 4096);
        }
        #pragma unroll
        for (int t = 0; t < 2; t++) {
            int bufi = (2 * p + t) % 6;
            const unsigned char* Ab = As[bufi];
            const unsigned char* Bb = Bs[bufi];
            long long av[4], bv[2];
            #pragma unroll
            for (int i = 0; i < 4; i++) av[i] = *(const long long*)(Ab + offA[i]);
            #pragma unroll
            for (int j = 0; j < 2; j++) bv[j] = *(const long long*)(Bb + offB[j]);
            #pragma unroll
            for (int i = 0; i < 4; i++)
                #pragma unroll
                for (int j = 0; j < 2; j++)
                    acc[i][j] = __builtin_amdgcn_mfma_f32_16x16x32_fp8_fp8(av[i], bv[j], acc[i][j], 0, 0, 0);
        }
    }

    // epilogue: S = sq_i + sq_j - 2*sw*G', masked softplus, x2 off-diagonal
    __syncthreads();
    if (tid < 128)      { sqI[tid] = sq[it * 128 + tid]; tIs[tid] = tgt[it * 128 + tid]; }
    else if (tid < 256) { int u = tid - 128; sqJ[u] = sq[jt * 128 + u]; tJs[u] = tgt[jt * 128 + u]; }
    __syncthreads();

    float sw2 = 2.0f * scal[0];
    float sum = 0.f;
    bool diagTile = (it == jt);
    #pragma unroll
    for (int j = 0; j < 2; j++) {
        int col = wcol + j * 16 + (lane & 15);            // C/D: col = lane&15
        float sj = sqJ[col]; int tj = tJs[col];
        #pragma unroll
        for (int i = 0; i < 4; i++) {
            int rbase = wrow + i * 16 + (lane >> 4) * 4;  // C/D: row = quad*4+reg
            #pragma unroll
            for (int rr = 0; rr < 4; rr++) {
                int rowp = rbase + rr;
                float S = sqI[rowp] + sj - sw2 * acc[i][j][rr];
                float v;
                if (tIs[rowp] == tj) v = (diagTile && rowp == col) ? 0.f : softplus(-S);
                else                 v = softplus(S);
                sum += v;
            }
        }
    }
    float scale = (diagTile ? 1.f : 2.f) * (1.f / ((float)N_ROWS * (float)(N_ROWS - 1)));
    sum *= scale;
    for (int off = 32; off; off >>= 1) sum += __shfl_down(sum, off, 64);
    if (lane == 0) red[wave] = sum;
    __syncthreads();
    if (tid == 0) {
        float t = 0.f;
        #pragma unroll
        for (int wv = 0; wv < 8; wv++) t += red[wv];
        atomicAdd(loss, t);
    }
}

extern "C" void kernel_launch(void* const* d_in, const int* in_sizes, int n_in,
                              void* d_out, int out_size, void* d_ws, size_t ws_size,
                              hipStream_t stream) {
    const float* X  = (const float*)d_in[0];
    const int* tgt  = (const int*)d_in[1];
    float* out = (float*)d_out;
    char* ws = (char*)d_ws;
    const size_t MB = 1u << 20;

    float* w      = (float*)ws;                         // 4 KB
    float* sq     = (float*)(ws + 4096);                // 16 KB
    float* scal   = (float*)(ws + 24576);               // 4 B
    unsigned int* Xb8  = (unsigned int*)(ws + 1 * MB);  // 4 MB
    unsigned int* XWb8 = (unsigned int*)(ws + 5 * MB);  // 4 MB
    float* csumR  = (float*)(ws + 9 * MB);              // 256 KB
    float* csqR   = (float*)(ws + 9 * MB + 256 * 1024); // 256 KB

    k_cstats  <<<256,  256, 0, stream>>>(X, tgt, csumR, csqR);
    k_weights <<<8,    128, 0, stream>>>(tgt, csumR, csqR, w, scal, out);
    k_prep    <<<4096, 256, 0, stream>>>(X, w, scal, Xb8, XWb8, sq);
    k_gemm_loss<<<528, 512, 0, stream>>>((const unsigned char*)Xb8, (const unsigned char*)XWb8,
                                         sq, tgt, scal, out);
}